// Round 1
// baseline (94.407 us; speedup 1.0000x reference)
//
#include <hip/hip_runtime.h>

// Shift3x3: depthwise 3x3 conv with one-hot kernels == per-channel spatial shift.
// x: (32, 576, 56, 56) fp32. 576 % 9 == 0 -> 64 channels per shift direction.
// direction d = c/64, d in [0,9): di = d/3 - 1, dj = d%3 - 1
// out[n,c,h,w] = x[n,c,h+di,w+dj] with zero padding outside.

constexpr int N = 32, C = 576, H = 56, W = 56;
constexpr int HW = H * W;          // 3136
constexpr int W4 = W / 4;          // 14 float4 per row
constexpr unsigned TOTV = (unsigned)N * C * H * W4;  // 14,450,688 vec elements

__global__ void Shift3x3_58299886076391_kernel(const float* __restrict__ x,
                                               float* __restrict__ out) {
    for (unsigned v = blockIdx.x * blockDim.x + threadIdx.x; v < TOTV;
         v += gridDim.x * blockDim.x) {
        unsigned w4 = v % W4;
        unsigned t  = v / W4;
        unsigned h  = t % H;
        t /= H;
        unsigned c  = t % C;
        unsigned n  = t / C;

        int d  = (int)(c >> 6);    // 64 channels per direction
        int di = d / 3 - 1;
        int dj = d % 3 - 1;
        int hs = (int)h + di;

        float4 r = make_float4(0.f, 0.f, 0.f, 0.f);
        if (hs >= 0 && hs < H) {
            const float* row = x + (size_t)(n * C + c) * HW + (size_t)hs * W;
            int w0 = (int)(w4 * 4) + dj;
            if (dj == 0) {
                // aligned 16B load
                r = *reinterpret_cast<const float4*>(row + w0);
            } else {
                float* rp = reinterpret_cast<float*>(&r);
#pragma unroll
                for (int k = 0; k < 4; ++k) {
                    int ws = w0 + k;
                    if (ws >= 0 && ws < W) rp[k] = row[ws];
                }
            }
        }
        reinterpret_cast<float4*>(out)[v] = r;
    }
}

extern "C" void kernel_launch(void* const* d_in, const int* in_sizes, int n_in,
                              void* d_out, int out_size, void* d_ws, size_t ws_size,
                              hipStream_t stream) {
    const float* x = (const float*)d_in[0];
    // d_in[1] is the one-hot kernel; its content is fully determined by
    // make_shift_kernel(576) (64 channels per direction, no remainder), so the
    // shift mapping is hardcoded in the kernel.
    float* out = (float*)d_out;

    const int threads = 256;
    const int blocks  = 2048;  // 256 CUs * 8 blocks/CU; grid-stride covers the rest
    Shift3x3_58299886076391_kernel<<<blocks, threads, 0, stream>>>(x, out);
}

// Round 3
// 71.555 us; speedup vs baseline: 1.3194x; 1.3194x over previous
//
#include <hip/hip_runtime.h>

// Shift3x3: depthwise 3x3 conv with one-hot kernels == per-channel spatial shift.
// x: (32, 576, 56, 56) fp32. 576 % 9 == 0 -> 64 channels per shift direction.
// direction d = c/64, d in [0,9): di = d/3 - 1, dj = d%3 - 1
// out[n,c,h,w] = x[n,c,h+di,w+dj] with zero padding outside.
//
// Structure: one block per (n,c) plane -> shift params are block-uniform
// (SGPR), branches are scalar, no per-element div/mod beyond i/14.
// dj=+-1 handled as: aligned float4 load + one edge dword, register shuffle.

typedef float f32x4 __attribute__((ext_vector_type(4)));  // native vec: OK for nontemporal builtin

constexpr int N = 32, C = 576, H = 56, W = 56;
constexpr int HW = H * W;          // 3136 floats per plane
constexpr int W4 = W / 4;          // 14 float4 per row
constexpr int PV = HW / 4;         // 784 float4 per plane

__global__ void Shift3x3_58299886076391_kernel(const float* __restrict__ x,
                                               float* __restrict__ out) {
    const int p = blockIdx.x;            // n*C + c
    const int c = p % C;                 // block-uniform -> scalar
    const int d  = c >> 6;               // 64 channels per direction
    const int di = d / 3 - 1;
    const int dj = d % 3 - 1;

    const float* plane  = x   + (size_t)p * HW;
    float*       oplane = out + (size_t)p * HW;

    for (int i = threadIdx.x; i < PV; i += blockDim.x) {
        const int h  = i / W4;
        const int w4 = i - h * W4;
        const int hs = h + di;

        f32x4 r = (f32x4)(0.f);
        if (hs >= 0 && hs < H) {
            const float* row = plane + hs * W;
            const int wb = w4 * 4;
            const f32x4 a = *reinterpret_cast<const f32x4*>(row + wb);
            if (dj == 0) {                       // scalar (block-uniform) branch
                r = a;
            } else if (dj == 1) {
                const float e = (wb + 4 < W) ? row[wb + 4] : 0.f;
                r = (f32x4){a.y, a.z, a.w, e};
            } else {                             // dj == -1
                const float e = (wb > 0) ? row[wb - 1] : 0.f;
                r = (f32x4){e, a.x, a.y, a.z};
            }
        }
        __builtin_nontemporal_store(r, reinterpret_cast<f32x4*>(oplane) + i);
    }
}

extern "C" void kernel_launch(void* const* d_in, const int* in_sizes, int n_in,
                              void* d_out, int out_size, void* d_ws, size_t ws_size,
                              hipStream_t stream) {
    const float* x = (const float*)d_in[0];
    // d_in[1] is the one-hot kernel; content fully determined by
    // make_shift_kernel(576) (exactly 64 channels per direction), so the
    // shift mapping is hardcoded.
    float* out = (float*)d_out;

    const int threads = 256;
    const int blocks  = N * C;   // 18432 planes
    Shift3x3_58299886076391_kernel<<<blocks, threads, 0, stream>>>(x, out);
}